// Round 1
// baseline (8270.226 us; speedup 1.0000x reference)
//
#include <hip/hip_runtime.h>
#include <hip/hip_bf16.h>
#include <math.h>

// ---------------------------------------------------------------------------
// Qwen2 decoder layer, fp32 baseline.
//   H=16 q-heads, HK=4 kv-heads, D=128, HID=2048, INTER=8192, L=4096, NU=3072
//   SAMPLE_LENS=[2048,2048] -> block-causal mask derived as (p/2048)*2048
// ---------------------------------------------------------------------------

#define NU     3072
#define LPACK  4096
#define HIDN   2048
#define NH     16
#define NKV    4
#define HD     128
#define INTERN 8192
#define SAMPLE 2048
#define QKV_LD 3072          // q(2048) | k(512) | v(512)
#define EPSF   1e-6f

__device__ __forceinline__ void fma4(float4& a, float s, const float4 b) {
    a.x = fmaf(s, b.x, a.x); a.y = fmaf(s, b.y, a.y);
    a.z = fmaf(s, b.z, a.z); a.w = fmaf(s, b.w, a.w);
}
__device__ __forceinline__ float4 mul4s(const float4 a, float s) {
    return make_float4(a.x*s, a.y*s, a.z*s, a.w*s);
}
__device__ __forceinline__ float4 add4(const float4 a, const float4 b) {
    return make_float4(a.x+b.x, a.y+b.y, a.z+b.z, a.w+b.w);
}

// ---------------------------- tiny index kernels ---------------------------

__global__ __launch_bounds__(256) void inv_init_kernel(int* __restrict__ inv) {
    inv[blockIdx.x * 256 + threadIdx.x] = -1;            // grid 16
}
__global__ __launch_bounds__(256) void inv_set_kernel(const int* __restrict__ und,
                                                      int* __restrict__ inv) {
    int i = blockIdx.x * 256 + threadIdx.x;              // grid 12 -> 3072 exact
    inv[und[i]] = i;
}

// ------------------------------ row RMSNorm --------------------------------
// one block (256 thr) per row of 2048
__global__ __launch_bounds__(256) void rmsnorm_kernel(const float* __restrict__ in,
                                                      const float* __restrict__ w,
                                                      float* __restrict__ out) {
    int row = blockIdx.x;
    const float4* p = (const float4*)(in + (size_t)row * HIDN);
    float4 a = p[threadIdx.x * 2];
    float4 b = p[threadIdx.x * 2 + 1];
    float ss = a.x*a.x + a.y*a.y + a.z*a.z + a.w*a.w
             + b.x*b.x + b.y*b.y + b.z*b.z + b.w*b.w;
    #pragma unroll
    for (int off = 32; off > 0; off >>= 1) ss += __shfl_xor(ss, off);
    __shared__ float red[4];
    if ((threadIdx.x & 63) == 0) red[threadIdx.x >> 6] = ss;
    __syncthreads();
    float tot = red[0] + red[1] + red[2] + red[3];
    float sc  = rsqrtf(tot * (1.0f / HIDN) + EPSF);
    const float4* wp = (const float4*)w;
    float4 w0 = wp[threadIdx.x * 2], w1 = wp[threadIdx.x * 2 + 1];
    float4* o = (float4*)(out + (size_t)row * HIDN);
    o[threadIdx.x * 2]     = make_float4(a.x*sc*w0.x, a.y*sc*w0.y, a.z*sc*w0.z, a.w*sc*w0.w);
    o[threadIdx.x * 2 + 1] = make_float4(b.x*sc*w1.x, b.y*sc*w1.y, b.z*sc*w1.z, b.w*sc*w1.w);
}

// --------------------- per-head RMSNorm of q (in place) --------------------
// grid (NU, NH), 64 threads; each thread 2 elems of the 128-dim head vector
__global__ __launch_bounds__(64) void qnorm_kernel(float* __restrict__ qkv,
                                                   const float* __restrict__ w) {
    int i = blockIdx.x, h = blockIdx.y, t = threadIdx.x;
    float* p = qkv + (size_t)i * QKV_LD + h * HD;
    float2 v = *(const float2*)(p + t * 2);
    float ss = v.x*v.x + v.y*v.y;
    #pragma unroll
    for (int off = 32; off > 0; off >>= 1) ss += __shfl_xor(ss, off);
    float sc = rsqrtf(ss * (1.0f / HD) + EPSF);
    float2 wv = *(const float2*)(w + t * 2);
    float2 r  = make_float2(v.x*sc*wv.x, v.y*sc*wv.y);
    *(float2*)(p + t * 2) = r;
}

// ------------- scatter K (with RMSNorm) and V into packed [L] --------------
// grid (LPACK, NKV), 64 threads
__global__ __launch_bounds__(64) void scatter_kv_kernel(const float* __restrict__ qkv,
                                                        const int* __restrict__ inv,
                                                        const float* __restrict__ knw,
                                                        float* __restrict__ Kn,
                                                        float* __restrict__ Vn) {
    int l = blockIdx.x, hk = blockIdx.y, t = threadIdx.x;
    int i = inv[l];
    size_t ko = (size_t)l * (NKV * HD) + hk * HD + t * 2;
    if (i < 0) {
        *(float2*)(Kn + ko) = make_float2(0.f, 0.f);
        *(float2*)(Vn + ko) = make_float2(0.f, 0.f);
        return;
    }
    const float* kp = qkv + (size_t)i * QKV_LD + HIDN + hk * HD;
    float2 kv = *(const float2*)(kp + t * 2);
    float ss = kv.x*kv.x + kv.y*kv.y;
    #pragma unroll
    for (int off = 32; off > 0; off >>= 1) ss += __shfl_xor(ss, off);
    float sc = rsqrtf(ss * (1.0f / HD) + EPSF);
    float2 wv = *(const float2*)(knw + t * 2);
    *(float2*)(Kn + ko) = make_float2(kv.x*sc*wv.x, kv.y*sc*wv.y);
    const float* vp = qkv + (size_t)i * QKV_LD + HIDN + NKV * HD + hk * HD;
    float2 vv = *(const float2*)(vp + t * 2);
    *(float2*)(Vn + ko) = vv;
}

// ------------------------------ generic GEMM -------------------------------
// C[M,N] = A[M,K] * B[N,K]^T (+bias per col) (+addend elementwise)
// BM=BN=128, BK=16, 256 threads, 8x8 per thread. N tiles select one of up to
// three B segments (col boundaries n1, n2; tiles never straddle boundaries).
__global__ __launch_bounds__(256) void gemm_kernel(
        const float* __restrict__ A, int lda,
        const float* __restrict__ B0, const float* __restrict__ B1,
        const float* __restrict__ B2, int n1, int n2,
        const float* __restrict__ bias0, const float* __restrict__ bias1,
        const float* __restrict__ bias2,
        const float* __restrict__ addend,
        float* __restrict__ C, int ldc, int K) {
    __shared__ float As[16][132];
    __shared__ float Bs[16][132];
    const int tid = threadIdx.x;
    const int m0 = blockIdx.y * 128;
    const int n0 = blockIdx.x * 128;
    const float* B; const float* bias; int bcol;
    if (n0 < n1)      { B = B0; bias = bias0; bcol = n0; }
    else if (n0 < n2) { B = B1; bias = bias1; bcol = n0 - n1; }
    else              { B = B2; bias = bias2; bcol = n0 - n2; }
    const int r  = tid >> 2;            // 0..63
    const int kc = (tid & 3) << 2;      // 0,4,8,12
    const float* Ap0 = A + (size_t)(m0 + r) * lda + kc;
    const float* Ap1 = Ap0 + (size_t)64 * lda;
    const float* Bp0 = B + (size_t)(bcol + r) * K + kc;
    const float* Bp1 = Bp0 + (size_t)64 * K;
    const int ty4 = (tid >> 4) << 2;    // 0..60
    const int tx4 = (tid & 15) << 2;    // 0..60
    float4 acc[2][4][2];
    #pragma unroll
    for (int ia = 0; ia < 2; ++ia)
        #pragma unroll
        for (int i = 0; i < 4; ++i)
            #pragma unroll
            for (int jb = 0; jb < 2; ++jb)
                acc[ia][i][jb] = make_float4(0.f, 0.f, 0.f, 0.f);

    for (int k0 = 0; k0 < K; k0 += 16) {
        float4 a0 = *(const float4*)(Ap0 + k0);
        float4 a1 = *(const float4*)(Ap1 + k0);
        float4 b0 = *(const float4*)(Bp0 + k0);
        float4 b1 = *(const float4*)(Bp1 + k0);
        As[kc+0][r]    = a0.x; As[kc+1][r]    = a0.y; As[kc+2][r]    = a0.z; As[kc+3][r]    = a0.w;
        As[kc+0][64+r] = a1.x; As[kc+1][64+r] = a1.y; As[kc+2][64+r] = a1.z; As[kc+3][64+r] = a1.w;
        Bs[kc+0][r]    = b0.x; Bs[kc+1][r]    = b0.y; Bs[kc+2][r]    = b0.z; Bs[kc+3][r]    = b0.w;
        Bs[kc+0][64+r] = b1.x; Bs[kc+1][64+r] = b1.y; Bs[kc+2][64+r] = b1.z; Bs[kc+3][64+r] = b1.w;
        __syncthreads();
        #pragma unroll
        for (int kk = 0; kk < 16; ++kk) {
            float4 av0 = *(const float4*)&As[kk][ty4];
            float4 av1 = *(const float4*)&As[kk][ty4 + 64];
            float4 bv0 = *(const float4*)&Bs[kk][tx4];
            float4 bv1 = *(const float4*)&Bs[kk][tx4 + 64];
            fma4(acc[0][0][0], av0.x, bv0); fma4(acc[0][0][1], av0.x, bv1);
            fma4(acc[0][1][0], av0.y, bv0); fma4(acc[0][1][1], av0.y, bv1);
            fma4(acc[0][2][0], av0.z, bv0); fma4(acc[0][2][1], av0.z, bv1);
            fma4(acc[0][3][0], av0.w, bv0); fma4(acc[0][3][1], av0.w, bv1);
            fma4(acc[1][0][0], av1.x, bv0); fma4(acc[1][0][1], av1.x, bv1);
            fma4(acc[1][1][0], av1.y, bv0); fma4(acc[1][1][1], av1.y, bv1);
            fma4(acc[1][2][0], av1.z, bv0); fma4(acc[1][2][1], av1.z, bv1);
            fma4(acc[1][3][0], av1.w, bv0); fma4(acc[1][3][1], av1.w, bv1);
        }
        __syncthreads();
    }
    float4 bb0 = make_float4(0.f,0.f,0.f,0.f), bb1 = bb0;
    if (bias) {
        bb0 = *(const float4*)(bias + bcol + tx4);
        bb1 = *(const float4*)(bias + bcol + 64 + tx4);
    }
    #pragma unroll
    for (int ia = 0; ia < 2; ++ia) {
        #pragma unroll
        for (int i = 0; i < 4; ++i) {
            int row = m0 + ia * 64 + ty4 + i;
            float4 v0 = add4(acc[ia][i][0], bb0);
            float4 v1 = add4(acc[ia][i][1], bb1);
            if (addend) {
                v0 = add4(v0, *(const float4*)(addend + (size_t)row * ldc + n0 + tx4));
                v1 = add4(v1, *(const float4*)(addend + (size_t)row * ldc + n0 + 64 + tx4));
            }
            *(float4*)(C + (size_t)row * ldc + n0 + tx4)      = v0;
            *(float4*)(C + (size_t)row * ldc + n0 + 64 + tx4) = v1;
        }
    }
}

// --------------------- fused gate/up GEMM with SwiGLU ----------------------
// act[M, INTER] = silu(A*Wg^T) * (A*Wu^T);  BM=128, BN=64, BK=16, 8 rows x 4 cols
__global__ __launch_bounds__(256) void gemm_gateup_kernel(
        const float* __restrict__ A,
        const float* __restrict__ Bg, const float* __restrict__ Bu,
        float* __restrict__ act) {
    __shared__ float As[16][132];
    __shared__ float Gs[16][68];
    __shared__ float Us[16][68];
    const int tid = threadIdx.x;
    const int m0 = blockIdx.y * 128;
    const int n0 = blockIdx.x * 64;
    const int r  = tid >> 2;
    const int kc = (tid & 3) << 2;
    const float* Ap0 = A  + (size_t)(m0 + r) * HIDN + kc;
    const float* Ap1 = Ap0 + (size_t)64 * HIDN;
    const float* Gp  = Bg + (size_t)(n0 + r) * HIDN + kc;
    const float* Up  = Bu + (size_t)(n0 + r) * HIDN + kc;
    const int ty4 = (tid >> 4) << 2;
    const int tx4 = (tid & 15) << 2;
    float4 ag[2][4], au[2][4];
    #pragma unroll
    for (int ia = 0; ia < 2; ++ia)
        #pragma unroll
        for (int i = 0; i < 4; ++i) {
            ag[ia][i] = make_float4(0.f,0.f,0.f,0.f);
            au[ia][i] = make_float4(0.f,0.f,0.f,0.f);
        }
    for (int k0 = 0; k0 < HIDN; k0 += 16) {
        float4 a0 = *(const float4*)(Ap0 + k0);
        float4 a1 = *(const float4*)(Ap1 + k0);
        float4 g0 = *(const float4*)(Gp + k0);
        float4 u0 = *(const float4*)(Up + k0);
        As[kc+0][r]    = a0.x; As[kc+1][r]    = a0.y; As[kc+2][r]    = a0.z; As[kc+3][r]    = a0.w;
        As[kc+0][64+r] = a1.x; As[kc+1][64+r] = a1.y; As[kc+2][64+r] = a1.z; As[kc+3][64+r] = a1.w;
        Gs[kc+0][r] = g0.x; Gs[kc+1][r] = g0.y; Gs[kc+2][r] = g0.z; Gs[kc+3][r] = g0.w;
        Us[kc+0][r] = u0.x; Us[kc+1][r] = u0.y; Us[kc+2][r] = u0.z; Us[kc+3][r] = u0.w;
        __syncthreads();
        #pragma unroll
        for (int kk = 0; kk < 16; ++kk) {
            float4 av0 = *(const float4*)&As[kk][ty4];
            float4 av1 = *(const float4*)&As[kk][ty4 + 64];
            float4 gv  = *(const float4*)&Gs[kk][tx4];
            float4 uv  = *(const float4*)&Us[kk][tx4];
            fma4(ag[0][0], av0.x, gv); fma4(au[0][0], av0.x, uv);
            fma4(ag[0][1], av0.y, gv); fma4(au[0][1], av0.y, uv);
            fma4(ag[0][2], av0.z, gv); fma4(au[0][2], av0.z, uv);
            fma4(ag[0][3], av0.w, gv); fma4(au[0][3], av0.w, uv);
            fma4(ag[1][0], av1.x, gv); fma4(au[1][0], av1.x, uv);
            fma4(ag[1][1], av1.y, gv); fma4(au[1][1], av1.y, uv);
            fma4(ag[1][2], av1.z, gv); fma4(au[1][2], av1.z, uv);
            fma4(ag[1][3], av1.w, gv); fma4(au[1][3], av1.w, uv);
        }
        __syncthreads();
    }
    #pragma unroll
    for (int ia = 0; ia < 2; ++ia) {
        #pragma unroll
        for (int i = 0; i < 4; ++i) {
            int row = m0 + ia * 64 + ty4 + i;
            float4 g = ag[ia][i], u = au[ia][i];
            float4 s;
            s.x = g.x / (1.f + __expf(-g.x));
            s.y = g.y / (1.f + __expf(-g.y));
            s.z = g.z / (1.f + __expf(-g.z));
            s.w = g.w / (1.f + __expf(-g.w));
            *(float4*)(act + (size_t)row * INTERN + n0 + tx4) =
                make_float4(s.x*u.x, s.y*u.y, s.z*u.z, s.w*u.w);
        }
    }
}

// ------------------------- flash attention (fp32) --------------------------
// grid (NU/32, NH), 256 threads. Q compact (und rows) from qkv; K/V packed.
__global__ __launch_bounds__(256) void attn_kernel(
        const float* __restrict__ qn,    // qkv base, q at col h*128, ld 3072
        const float* __restrict__ Kn,    // [4096][512]
        const float* __restrict__ Vn,    // [4096][512]
        const int* __restrict__ und,     // [3072] sorted
        float* __restrict__ ctx) {       // [3072][2048]
    const int h  = blockIdx.y, hk = h >> 2;
    const int i0 = blockIdx.x * 32;
    const int tid = threadIdx.x;
    __shared__ float Qs[32][132];
    __shared__ float Ks[32][132];
    __shared__ float Vs[32][128];
    __shared__ float Ss[32][36];
    __shared__ float cs[32], msh[32], lsh[32];
    __shared__ int   pq[32], rs[32];

    {   // stage Q tile
        int r = tid >> 3, c = (tid & 7) << 4;
        const float* src = qn + (size_t)(i0 + r) * QKV_LD + h * HD + c;
        #pragma unroll
        for (int m = 0; m < 4; ++m)
            *(float4*)&Qs[r][c + 4*m] = *(const float4*)(src + 4*m);
    }
    if (tid < 32) {
        int p = und[i0 + tid];
        pq[tid] = p;
        rs[tid] = (p / SAMPLE) * SAMPLE;   // block-causal start
        msh[tid] = -1e30f; lsh[tid] = 0.f;
    }
    __syncthreads();
    const int kbeg = rs[0] & ~31;
    const int kend = pq[31];

    const int tq = tid >> 4, tk = tid & 15;   // S-compute: 2 q rows x 2 k cols
    const int q2 = tid >> 4, ds = tid & 15;   // PV: 2 q rows x 8 d (ds*4, ds*4+64)
    const int sq = tid >> 3, sc = tid & 7;    // softmax: row sq, cols sc*4..+3
    float4 o00 = make_float4(0,0,0,0), o01 = o00, o10 = o00, o11 = o00;
    const float SCALE = 0.08838834764831845f; // 1/sqrt(128)

    for (int k0 = kbeg; k0 <= kend; k0 += 32) {
        {   // stage K/V tile
            int r = tid >> 3, c = (tid & 7) << 4;
            const float* ksrc = Kn + (size_t)(k0 + r) * (NKV*HD) + hk * HD + c;
            const float* vsrc = Vn + (size_t)(k0 + r) * (NKV*HD) + hk * HD + c;
            #pragma unroll
            for (int m = 0; m < 4; ++m) {
                *(float4*)&Ks[r][c + 4*m] = *(const float4*)(ksrc + 4*m);
                *(float4*)&Vs[r][c + 4*m] = *(const float4*)(vsrc + 4*m);
            }
        }
        __syncthreads();
        // S = Q K^T  (2x2 per thread)
        float s00 = 0.f, s01 = 0.f, s10 = 0.f, s11 = 0.f;
        #pragma unroll
        for (int c = 0; c < 128; c += 4) {
            float4 qa = *(const float4*)&Qs[tq*2][c];
            float4 qb = *(const float4*)&Qs[tq*2+1][c];
            float4 ka = *(const float4*)&Ks[tk*2][c];
            float4 kb = *(const float4*)&Ks[tk*2+1][c];
            s00 += qa.x*ka.x + qa.y*ka.y + qa.z*ka.z + qa.w*ka.w;
            s01 += qa.x*kb.x + qa.y*kb.y + qa.z*kb.z + qa.w*kb.w;
            s10 += qb.x*ka.x + qb.y*ka.y + qb.z*ka.z + qb.w*ka.w;
            s11 += qb.x*kb.x + qb.y*kb.y + qb.z*kb.z + qb.w*kb.w;
        }
        {
            int q0i = tq*2, q1i = tq*2 + 1;
            int kp0 = k0 + tk*2, kp1 = kp0 + 1;
            Ss[q0i][tk*2]   = (kp0 >= rs[q0i] && kp0 <= pq[q0i]) ? s00*SCALE : -1e30f;
            Ss[q0i][tk*2+1] = (kp1 >= rs[q0i] && kp1 <= pq[q0i]) ? s01*SCALE : -1e30f;
            Ss[q1i][tk*2]   = (kp0 >= rs[q1i] && kp0 <= pq[q1i]) ? s10*SCALE : -1e30f;
            Ss[q1i][tk*2+1] = (kp1 >= rs[q1i] && kp1 <= pq[q1i]) ? s11*SCALE : -1e30f;
        }
        __syncthreads();
        // online softmax (8 lanes per row)
        {
            float4 sv = *(const float4*)&Ss[sq][sc*4];
            float mt = fmaxf(fmaxf(sv.x, sv.y), fmaxf(sv.z, sv.w));
            mt = fmaxf(mt, __shfl_xor(mt, 1));
            mt = fmaxf(mt, __shfl_xor(mt, 2));
            mt = fmaxf(mt, __shfl_xor(mt, 4));
            float mold = msh[sq];
            float mnew = fmaxf(mold, mt);
            float corr = __expf(mold - mnew);
            float4 pv;
            pv.x = sv.x > -1e29f ? __expf(sv.x - mnew) : 0.f;
            pv.y = sv.y > -1e29f ? __expf(sv.y - mnew) : 0.f;
            pv.z = sv.z > -1e29f ? __expf(sv.z - mnew) : 0.f;
            pv.w = sv.w > -1e29f ? __expf(sv.w - mnew) : 0.f;
            float psum = pv.x + pv.y + pv.z + pv.w;
            psum += __shfl_xor(psum, 1);
            psum += __shfl_xor(psum, 2);
            psum += __shfl_xor(psum, 4);
            *(float4*)&Ss[sq][sc*4] = pv;
            if (sc == 0) {
                msh[sq] = mnew;
                lsh[sq] = lsh[sq] * corr + psum;
                cs[sq]  = corr;
            }
        }
        __syncthreads();
        // PV accumulate
        {
            float c0 = cs[q2*2], c1 = cs[q2*2 + 1];
            o00 = mul4s(o00, c0); o01 = mul4s(o01, c0);
            o10 = mul4s(o10, c1); o11 = mul4s(o11, c1);
            #pragma unroll
            for (int kk = 0; kk < 32; kk += 4) {
                float4 p0 = *(const float4*)&Ss[q2*2][kk];
                float4 p1 = *(const float4*)&Ss[q2*2 + 1][kk];
                {
                    float4 va = *(const float4*)&Vs[kk][ds*4];
                    float4 vb = *(const float4*)&Vs[kk][ds*4 + 64];
                    fma4(o00, p0.x, va); fma4(o01, p0.x, vb);
                    fma4(o10, p1.x, va); fma4(o11, p1.x, vb);
                }
                {
                    float4 va = *(const float4*)&Vs[kk+1][ds*4];
                    float4 vb = *(const float4*)&Vs[kk+1][ds*4 + 64];
                    fma4(o00, p0.y, va); fma4(o01, p0.y, vb);
                    fma4(o10, p1.y, va); fma4(o11, p1.y, vb);
                }
                {
                    float4 va = *(const float4*)&Vs[kk+2][ds*4];
                    float4 vb = *(const float4*)&Vs[kk+2][ds*4 + 64];
                    fma4(o00, p0.z, va); fma4(o01, p0.z, vb);
                    fma4(o10, p1.z, va); fma4(o11, p1.z, vb);
                }
                {
                    float4 va = *(const float4*)&Vs[kk+3][ds*4];
                    float4 vb = *(const float4*)&Vs[kk+3][ds*4 + 64];
                    fma4(o00, p0.w, va); fma4(o01, p0.w, vb);
                    fma4(o10, p1.w, va); fma4(o11, p1.w, vb);
                }
            }
        }
        __syncthreads();
    }
    float il0 = 1.f / lsh[q2*2];
    float il1 = 1.f / lsh[q2*2 + 1];
    float* dst0 = ctx + (size_t)(i0 + q2*2) * HIDN + h * HD;
    float* dst1 = dst0 + HIDN;
    *(float4*)(dst0 + ds*4)      = mul4s(o00, il0);
    *(float4*)(dst0 + ds*4 + 64) = mul4s(o01, il0);
    *(float4*)(dst1 + ds*4)      = mul4s(o10, il1);
    *(float4*)(dst1 + ds*4 + 64) = mul4s(o11, il1);
}

// ---------------------------------------------------------------------------

extern "C" void kernel_launch(void* const* d_in, const int* in_sizes, int n_in,
                              void* d_out, int out_size, void* d_ws, size_t ws_size,
                              hipStream_t stream) {
    const float* x    = (const float*)d_in[0];   // [3072][2048]
    const int*   und  = (const int*)d_in[1];     // [3072] sorted
    // d_in[2]=cos, d_in[3]=sin (unused: reference attention is pre-RoPE)
    // d_in[4]=mask (unused: block-causal structure derived from p/2048)
    const float* Wq  = (const float*)d_in[5];
    const float* bq  = (const float*)d_in[6];
    const float* Wk  = (const float*)d_in[7];
    const float* bk  = (const float*)d_in[8];
    const float* Wv  = (const float*)d_in[9];
    const float* bv  = (const float*)d_in[10];
    const float* Wo  = (const float*)d_in[11];
    const float* qnw = (const float*)d_in[12];
    const float* knw = (const float*)d_in[13];
    const float* ln1 = (const float*)d_in[14];
    const float* ln2 = (const float*)d_in[15];
    const float* Wg  = (const float*)d_in[16];
    const float* Wu  = (const float*)d_in[17];
    const float* Wd  = (const float*)d_in[18];
    float* out = (float*)d_out;

    float* ws = (float*)d_ws;
    float* xn   = ws;                       // 6291456   (also reused as ctx)
    float* qkv  = ws + 6291456;             // 9437184   (also reused as y)
    float* Kn   = ws + 15728640;            // 2097152
    float* Vn   = ws + 17825792;            // 2097152
    float* hbuf = ws + 19922944;            // 6291456
    float* act  = ws + 26214400;            // 25165824
    int*   inv  = (int*)(ws + 51380224);    // 4096 ints
    float* ctx  = xn;
    float* ybuf = qkv;

    // index map
    inv_init_kernel<<<16, 256, 0, stream>>>(inv);
    inv_set_kernel<<<12, 256, 0, stream>>>(und, inv);
    // ln1 RMSNorm
    rmsnorm_kernel<<<NU, 256, 0, stream>>>(x, ln1, xn);
    // fused QKV projection (+bias): qkv[3072][3072]
    gemm_kernel<<<dim3(24, 24), 256, 0, stream>>>(
        xn, HIDN, Wq, Wk, Wv, 2048, 2560, bq, bk, bv,
        nullptr, qkv, QKV_LD, HIDN);
    // q-head RMSNorm in place; scatter+norm K, scatter V
    qnorm_kernel<<<dim3(NU, NH), 64, 0, stream>>>(qkv, qnw);
    scatter_kv_kernel<<<dim3(LPACK, NKV), 64, 0, stream>>>(qkv, inv, knw, Kn, Vn);
    // attention -> ctx
    attn_kernel<<<dim3(NU / 32, NH), 256, 0, stream>>>(qkv, Kn, Vn, und, ctx);
    // h = ctx @ Wo^T + resid
    gemm_kernel<<<dim3(16, 24), 256, 0, stream>>>(
        ctx, HIDN, Wo, nullptr, nullptr, HIDN, HIDN,
        nullptr, nullptr, nullptr, x, hbuf, HIDN, HIDN);
    // y = rmsnorm(h, ln2)
    rmsnorm_kernel<<<NU, 256, 0, stream>>>(hbuf, ln2, ybuf);
    // act = silu(y@Wg^T) * (y@Wu^T)
    gemm_gateup_kernel<<<dim3(INTERN / 64, 24), 256, 0, stream>>>(ybuf, Wg, Wu, act);
    // out = h + act @ Wd^T
    gemm_kernel<<<dim3(16, 24), 256, 0, stream>>>(
        act, INTERN, Wd, nullptr, nullptr, HIDN, HIDN,
        nullptr, nullptr, nullptr, hbuf, out, HIDN, INTERN);
}

// Round 2
// 734.983 us; speedup vs baseline: 11.2523x; 11.2523x over previous
//
#include <hip/hip_runtime.h>
#include <math.h>

// ---------------------------------------------------------------------------
// Qwen2 decoder layer, bf16-MFMA version (gfx950).
//   H=16 q-heads, HK=4 kv-heads, D=128, HID=2048, INTER=8192, L=4096, NU=3072
//   block-causal mask derived from (p >> 11) << 11  (SAMPLE=2048)
// ---------------------------------------------------------------------------

#define NU     3072
#define LPACK  4096
#define HIDN   2048
#define QKV_LD 3072
#define EPSF   1e-6f

typedef unsigned short u16;
typedef unsigned int   u32;
typedef __attribute__((ext_vector_type(8)))  __bf16 bf16x8;
typedef __attribute__((ext_vector_type(4)))  float  f32x4;
typedef __attribute__((ext_vector_type(16))) float  f32x16;

union FRAG { uint4 q; u16 u[8]; bf16x8 b; };

__device__ __forceinline__ u16 f2bf(float f) {
    u32 u = __float_as_uint(f);
    u32 r = (u + 0x7fffu + ((u >> 16) & 1u)) >> 16;
    return (u16)r;
}
__device__ __forceinline__ float bf2f(u16 h) {
    return __uint_as_float(((u32)h) << 16);
}
__device__ __forceinline__ void gload_lds16(const u16* g, u16* lds) {
    __builtin_amdgcn_global_load_lds(
        (const __attribute__((address_space(1))) u32*)g,
        (__attribute__((address_space(3))) u32*)lds, 16, 0, 0);
}

// ---------------------------- tiny index kernels ---------------------------

__global__ __launch_bounds__(256) void inv_init_kernel(int* __restrict__ inv) {
    inv[blockIdx.x * 256 + threadIdx.x] = -1;            // grid 16
}
__global__ __launch_bounds__(256) void inv_set_kernel(const int* __restrict__ und,
                                                      int* __restrict__ inv) {
    int i = blockIdx.x * 256 + threadIdx.x;              // grid 12
    inv[und[i]] = i;
}

// --------------------------- fp32 -> bf16 convert --------------------------

__global__ __launch_bounds__(256) void cvt_bf16_kernel(const float* __restrict__ in,
                                                       u16* __restrict__ out, int n8) {
    int idx = blockIdx.x * 256 + threadIdx.x;
    int stride = gridDim.x * 256;
    for (int i = idx; i < n8; i += stride) {
        float4 a = *(const float4*)(in + (size_t)i * 8);
        float4 b = *(const float4*)(in + (size_t)i * 8 + 4);
        FRAG f;
        f.u[0] = f2bf(a.x); f.u[1] = f2bf(a.y); f.u[2] = f2bf(a.z); f.u[3] = f2bf(a.w);
        f.u[4] = f2bf(b.x); f.u[5] = f2bf(b.y); f.u[6] = f2bf(b.z); f.u[7] = f2bf(b.w);
        *(uint4*)(out + (size_t)i * 8) = f.q;
    }
}

// ---------------------- row RMSNorm (fp32 in, bf16 out) --------------------

__global__ __launch_bounds__(256) void rmsnorm_bf16_kernel(const float* __restrict__ in,
                                                           const float* __restrict__ w,
                                                           u16* __restrict__ out) {
    int row = blockIdx.x;
    const float4* p = (const float4*)(in + (size_t)row * HIDN);
    float4 a = p[threadIdx.x * 2];
    float4 b = p[threadIdx.x * 2 + 1];
    float ss = a.x*a.x + a.y*a.y + a.z*a.z + a.w*a.w
             + b.x*b.x + b.y*b.y + b.z*b.z + b.w*b.w;
    #pragma unroll
    for (int off = 32; off > 0; off >>= 1) ss += __shfl_xor(ss, off, 64);
    __shared__ float red[4];
    if ((threadIdx.x & 63) == 0) red[threadIdx.x >> 6] = ss;
    __syncthreads();
    float tot = red[0] + red[1] + red[2] + red[3];
    float sc  = rsqrtf(tot * (1.0f / HIDN) + EPSF);
    const float4* wp = (const float4*)w;
    float4 w0 = wp[threadIdx.x * 2], w1 = wp[threadIdx.x * 2 + 1];
    FRAG f;
    f.u[0] = f2bf(a.x*sc*w0.x); f.u[1] = f2bf(a.y*sc*w0.y);
    f.u[2] = f2bf(a.z*sc*w0.z); f.u[3] = f2bf(a.w*sc*w0.w);
    f.u[4] = f2bf(b.x*sc*w1.x); f.u[5] = f2bf(b.y*sc*w1.y);
    f.u[6] = f2bf(b.z*sc*w1.z); f.u[7] = f2bf(b.w*sc*w1.w);
    *(uint4*)(out + (size_t)row * HIDN + threadIdx.x * 8) = f.q;
}

// --------------------- per-head RMSNorm of q (bf16 in place) ---------------

__global__ __launch_bounds__(64) void qnorm_kernel(u16* __restrict__ qkv,
                                                   const float* __restrict__ w) {
    int i = blockIdx.x, h = blockIdx.y, t = threadIdx.x;
    u16* p = qkv + (size_t)i * QKV_LD + h * 128 + t * 2;
    u32 pr = *(u32*)p;
    float x0 = bf2f((u16)(pr & 0xffff)), x1 = bf2f((u16)(pr >> 16));
    float ss = x0*x0 + x1*x1;
    #pragma unroll
    for (int off = 32; off > 0; off >>= 1) ss += __shfl_xor(ss, off, 64);
    float sc = rsqrtf(ss * (1.0f / 128.f) + EPSF);
    float2 wv = *(const float2*)(w + t * 2);
    u32 res = (u32)f2bf(x0*sc*wv.x) | ((u32)f2bf(x1*sc*wv.y) << 16);
    *(u32*)p = res;
}

// ------------- scatter K (with RMSNorm) and V into packed [L], bf16 --------

__global__ __launch_bounds__(64) void scatter_kv_kernel(const u16* __restrict__ qkvb,
                                                        const int* __restrict__ inv,
                                                        const float* __restrict__ knw,
                                                        u16* __restrict__ Kb,
                                                        u16* __restrict__ Vb) {
    int l = blockIdx.x, hkk = blockIdx.y, t = threadIdx.x;
    int i = inv[l];
    size_t off = (size_t)l * 512 + hkk * 128 + t * 2;
    if (i < 0) {
        *(u32*)(Kb + off) = 0u;
        *(u32*)(Vb + off) = 0u;
        return;
    }
    const u16* kp = qkvb + (size_t)i * QKV_LD + 2048 + hkk * 128 + t * 2;
    u32 kv = *(const u32*)kp;
    float k0 = bf2f((u16)(kv & 0xffff)), k1 = bf2f((u16)(kv >> 16));
    float ss = k0*k0 + k1*k1;
    #pragma unroll
    for (int off2 = 32; off2 > 0; off2 >>= 1) ss += __shfl_xor(ss, off2, 64);
    float sc = rsqrtf(ss * (1.0f / 128.f) + EPSF);
    float2 wv = *(const float2*)(knw + t * 2);
    u32 res = (u32)f2bf(k0*sc*wv.x) | ((u32)f2bf(k1*sc*wv.y) << 16);
    *(u32*)(Kb + off) = res;
    const u16* vp = qkvb + (size_t)i * QKV_LD + 2560 + hkk * 128 + t * 2;
    *(u32*)(Vb + off) = *(const u32*)vp;
}

// ------------------------------ bf16 MFMA GEMM -----------------------------
// C[M,N] = A[M,K] * B[N,K]^T, 128x128 tile, BK=64, 4 waves, 16x16x32 MFMA.
// LDS XOR-swizzle: 16B-block j of row r stored at j ^ (r&7) (both sides).
// MODE 0: segmented B + bias, bf16 out.  MODE 1: +addend, fp32 out.

template <int MODE>
__global__ __launch_bounds__(256, 2) void gemm_bf16_kernel(
        const u16* __restrict__ A, int lda,
        const u16* __restrict__ B0, const u16* __restrict__ B1, const u16* __restrict__ B2,
        int n1, int n2, int ldb,
        const float* __restrict__ bias0, const float* __restrict__ bias1,
        const float* __restrict__ bias2,
        const float* __restrict__ addend,
        void* __restrict__ Cout, int ldc, int K)
{
    __shared__ u16 As[128 * 64];
    __shared__ u16 Bs[128 * 64];
    const int tid = threadIdx.x;
    const int w = tid >> 6, lane = tid & 63;
    const int m0 = blockIdx.y * 128, n0 = blockIdx.x * 128;
    const u16* Bp; const float* bias; int nb;
    if (n0 < n1)      { Bp = B0; bias = bias0; nb = n0; }
    else if (n0 < n2) { Bp = B1; bias = bias1; nb = n0 - n1; }
    else              { Bp = B2; bias = bias2; nb = n0 - n2; }
    const int wr = w >> 1, wc = w & 1;
    const int cl = lane & 15, kg = lane >> 4;

    f32x4 acc[4][4];
    #pragma unroll
    for (int i = 0; i < 4; ++i)
        #pragma unroll
        for (int j = 0; j < 4; ++j)
            #pragma unroll
            for (int r = 0; r < 4; ++r) acc[i][j][r] = 0.f;

    for (int k0 = 0; k0 < K; k0 += 64) {
        #pragma unroll
        for (int j = 0; j < 4; ++j) {
            int slot = j * 256 + tid;
            int row = slot >> 3, jp = slot & 7;
            int j2 = jp ^ (row & 7);
            gload_lds16(A + (size_t)(m0 + row) * lda + k0 + j2 * 8,
                        &As[(j * 256 + w * 64) * 8]);
        }
        #pragma unroll
        for (int j = 0; j < 4; ++j) {
            int slot = j * 256 + tid;
            int row = slot >> 3, jp = slot & 7;
            int j2 = jp ^ (row & 7);
            gload_lds16(Bp + (size_t)(nb + row) * ldb + k0 + j2 * 8,
                        &Bs[(j * 256 + w * 64) * 8]);
        }
        __syncthreads();
        #pragma unroll
        for (int ks = 0; ks < 2; ++ks) {
            FRAG af[4], bfr[4];
            #pragma unroll
            for (int mi = 0; mi < 4; ++mi) {
                int row = wr * 64 + mi * 16 + cl;
                int dblk = ks * 4 + kg;
                af[mi].q = *(const uint4*)&As[row * 64 + ((dblk ^ (row & 7)) * 8)];
            }
            #pragma unroll
            for (int ni = 0; ni < 4; ++ni) {
                int row = wc * 64 + ni * 16 + cl;
                int dblk = ks * 4 + kg;
                bfr[ni].q = *(const uint4*)&Bs[row * 64 + ((dblk ^ (row & 7)) * 8)];
            }
            #pragma unroll
            for (int mi = 0; mi < 4; ++mi)
                #pragma unroll
                for (int ni = 0; ni < 4; ++ni)
                    acc[mi][ni] = __builtin_amdgcn_mfma_f32_16x16x32_bf16(
                        af[mi].b, bfr[ni].b, acc[mi][ni], 0, 0, 0);
        }
        __syncthreads();
    }
    #pragma unroll
    for (int mi = 0; mi < 4; ++mi) {
        #pragma unroll
        for (int ni = 0; ni < 4; ++ni) {
            int gcol = n0 + wc * 64 + ni * 16 + cl;
            float bv = 0.f;
            if (MODE == 0) bv = bias[nb + wc * 64 + ni * 16 + cl];
            #pragma unroll
            for (int r = 0; r < 4; ++r) {
                int grow = m0 + wr * 64 + mi * 16 + kg * 4 + r;
                float v = acc[mi][ni][r] + bv;
                if (MODE == 0) {
                    ((u16*)Cout)[(size_t)grow * ldc + gcol] = f2bf(v);
                } else {
                    v += addend[(size_t)grow * ldc + gcol];
                    ((float*)Cout)[(size_t)grow * ldc + gcol] = v;
                }
            }
        }
    }
}

// --------------------- fused gate/up GEMM with SwiGLU (bf16) ---------------

__global__ __launch_bounds__(256, 2) void gemm_gateup_bf16_kernel(
        const u16* __restrict__ A,
        const u16* __restrict__ Bg, const u16* __restrict__ Bu,
        u16* __restrict__ act, int ldc)
{
    __shared__ u16 As[128 * 64];
    __shared__ u16 Gs[128 * 64];
    __shared__ u16 Us[128 * 64];
    const int tid = threadIdx.x;
    const int w = tid >> 6, lane = tid & 63;
    const int m0 = blockIdx.y * 128, n0 = blockIdx.x * 128;
    const int wr = w >> 1, wc = w & 1;
    const int cl = lane & 15, kg = lane >> 4;

    f32x4 ag[4][4], au[4][4];
    #pragma unroll
    for (int i = 0; i < 4; ++i)
        #pragma unroll
        for (int j = 0; j < 4; ++j)
            #pragma unroll
            for (int r = 0; r < 4; ++r) { ag[i][j][r] = 0.f; au[i][j][r] = 0.f; }

    for (int k0 = 0; k0 < HIDN; k0 += 64) {
        #pragma unroll
        for (int j = 0; j < 4; ++j) {
            int slot = j * 256 + tid;
            int row = slot >> 3, jp = slot & 7;
            int j2 = jp ^ (row & 7);
            gload_lds16(A + (size_t)(m0 + row) * HIDN + k0 + j2 * 8,
                        &As[(j * 256 + w * 64) * 8]);
            gload_lds16(Bg + (size_t)(n0 + row) * HIDN + k0 + j2 * 8,
                        &Gs[(j * 256 + w * 64) * 8]);
            gload_lds16(Bu + (size_t)(n0 + row) * HIDN + k0 + j2 * 8,
                        &Us[(j * 256 + w * 64) * 8]);
        }
        __syncthreads();
        #pragma unroll
        for (int ks = 0; ks < 2; ++ks) {
            FRAG af[4], gf[4], uf[4];
            #pragma unroll
            for (int mi = 0; mi < 4; ++mi) {
                int row = wr * 64 + mi * 16 + cl;
                int dblk = ks * 4 + kg;
                af[mi].q = *(const uint4*)&As[row * 64 + ((dblk ^ (row & 7)) * 8)];
            }
            #pragma unroll
            for (int ni = 0; ni < 4; ++ni) {
                int row = wc * 64 + ni * 16 + cl;
                int dblk = ks * 4 + kg;
                gf[ni].q = *(const uint4*)&Gs[row * 64 + ((dblk ^ (row & 7)) * 8)];
                uf[ni].q = *(const uint4*)&Us[row * 64 + ((dblk ^ (row & 7)) * 8)];
            }
            #pragma unroll
            for (int mi = 0; mi < 4; ++mi)
                #pragma unroll
                for (int ni = 0; ni < 4; ++ni) {
                    ag[mi][ni] = __builtin_amdgcn_mfma_f32_16x16x32_bf16(
                        af[mi].b, gf[ni].b, ag[mi][ni], 0, 0, 0);
                    au[mi][ni] = __builtin_amdgcn_mfma_f32_16x16x32_bf16(
                        af[mi].b, uf[ni].b, au[mi][ni], 0, 0, 0);
                }
        }
        __syncthreads();
    }
    #pragma unroll
    for (int mi = 0; mi < 4; ++mi) {
        #pragma unroll
        for (int ni = 0; ni < 4; ++ni) {
            int gcol = n0 + wc * 64 + ni * 16 + cl;
            #pragma unroll
            for (int r = 0; r < 4; ++r) {
                int grow = m0 + wr * 64 + mi * 16 + kg * 4 + r;
                float g = ag[mi][ni][r], u = au[mi][ni][r];
                float s = g / (1.f + __expf(-g));
                act[(size_t)grow * ldc + gcol] = f2bf(s * u);
            }
        }
    }
}

// --------------------- MFMA flash attention (bf16, 32x32x16) ---------------
// 4 waves x 32 q-rows = 128 q per block, KT=32 keys per tile.
// Swapped QK^T: St = mfma(K, Q) -> lane owns q = lane&31 (softmax lane-local).
// PV A-frag built via cvt_pk + v_permlane32_swap_b32 (m214 recipe).

__global__ __launch_bounds__(256, 2) void attn_mfma_kernel(
        const u16* __restrict__ qkv,   // bf16 [3072][3072], q at h*128
        const u16* __restrict__ Kb,    // bf16 [4096][512]
        const u16* __restrict__ Vb,    // bf16 [4096][512]
        const int* __restrict__ und,   // [3072] sorted
        u16* __restrict__ ctxb)        // bf16 [3072][2048]
{
    const int h = blockIdx.y, hk = h >> 2;
    const int i0 = blockIdx.x * 128;
    const int tid = threadIdx.x;
    const int w = tid >> 6, lane = tid & 63;
    const int ql = lane & 31, hi = lane >> 5;

    __shared__ u16  Kt[32 * 128];      // swizzled: block j of row r at j^(r&15)
    __shared__ u16  Vt[128 * 40];      // V^T: Vt[d][key], rows padded to 40
    __shared__ float Ot[4][32][36];    // per-wave epilogue transpose

    const int iq  = i0 + w * 32 + ql;
    const int pqv = und[iq];
    const int rsv = pqv & ~2047;
    const int kend_w = __shfl(pqv, 31, 64);
    const int kbeg_w = __shfl(pqv, 0, 64) & ~2047;
    const int kbeg_b = und[i0] & ~2047;
    const int kend_b = und[i0 + 127];

    FRAG qf[8];
    const u16* qbase = qkv + (size_t)iq * QKV_LD + h * 128;
    #pragma unroll
    for (int ds = 0; ds < 8; ++ds)
        qf[ds].q = *(const uint4*)(qbase + ds * 16 + hi * 8);

    f32x16 Oa[4];
    #pragma unroll
    for (int dg = 0; dg < 4; ++dg)
        #pragma unroll
        for (int r = 0; r < 16; ++r) Oa[dg][r] = 0.f;
    float m_run = -1e30f, l_run = 0.f;
    const float SCALE = 0.08838834764831845f;   // 1/sqrt(128)

    for (int k0 = kbeg_b; k0 <= kend_b; k0 += 32) {
        // stage K (8 KB) via global_load_lds, pre-swizzled source
        #pragma unroll
        for (int j = 0; j < 2; ++j) {
            int sb = (j * 4 + w) * 64;
            int slot = sb + lane;
            int r = slot >> 4, jp = slot & 15;
            int jj = jp ^ (r & 15);
            gload_lds16(Kb + (size_t)(k0 + r) * 512 + hk * 128 + jj * 8, &Kt[sb * 8]);
        }
        // stage V transposed (reg-staged): kp = key pair, d0 = 8-d group
        {
            int kp = tid & 15, d0 = (tid >> 4) * 8;
            const u16* v0 = Vb + (size_t)(k0 + kp * 2) * 512 + hk * 128 + d0;
            FRAG r0, r1;
            r0.q = *(const uint4*)v0;
            r1.q = *(const uint4*)(v0 + 512);
            #pragma unroll
            for (int i = 0; i < 8; ++i) {
                u32 val = (u32)r0.u[i] | ((u32)r1.u[i] << 16);
                *(u32*)&Vt[(d0 + i) * 40 + kp * 2] = val;
            }
        }
        __syncthreads();
        if (k0 + 31 >= kbeg_w && k0 <= kend_w) {
            // St[key][q] over d=128 : 8 x mfma 32x32x16
            f32x16 st;
            #pragma unroll
            for (int r = 0; r < 16; ++r) st[r] = 0.f;
            #pragma unroll
            for (int ds = 0; ds < 8; ++ds) {
                FRAG kf;
                kf.q = *(const uint4*)&Kt[ql * 128 + (((ds * 2 + hi) ^ (ql & 15)) * 8)];
                st = __builtin_amdgcn_mfma_f32_32x32x16_bf16(kf.b, qf[ds].b, st, 0, 0, 0);
            }
            // mask + online softmax (lane owns q = ql; keys split by hi)
            float p[16];
            float mloc = -1e30f;
            #pragma unroll
            for (int r = 0; r < 16; ++r) {
                int key = k0 + (r & 3) + ((r >> 2) << 3) + (hi << 2);
                float s = (key >= rsv && key <= pqv) ? st[r] * SCALE : -1e30f;
                p[r] = s;
                mloc = fmaxf(mloc, s);
            }
            float mfull = fmaxf(mloc, __shfl_xor(mloc, 32, 64));
            float mnew = fmaxf(m_run, mfull);
            float corr = __expf(m_run - mnew);
            float psum = 0.f;
            #pragma unroll
            for (int r = 0; r < 16; ++r) {
                float e = (p[r] > -1e29f) ? __expf(p[r] - mnew) : 0.f;
                p[r] = e; psum += e;
            }
            psum += __shfl_xor(psum, 32, 64);
            l_run = l_run * corr + psum;
            if (__any(mnew > m_run)) {
                #pragma unroll
                for (int r = 0; r < 16; ++r) {
                    float cr = __shfl(corr, (r & 3) + ((r >> 2) << 3) + (hi << 2), 64);
                    #pragma unroll
                    for (int dg = 0; dg < 4; ++dg) Oa[dg][r] *= cr;
                }
            }
            m_run = mnew;
            // build PV A-frags: cvt_pk + permlane32_swap
            u32 pa[2][4];
            #pragma unroll
            for (int s = 0; s < 2; ++s) {
                #pragma unroll
                for (int t = 0; t < 2; ++t) {
                    u32 a = (u32)f2bf(p[8*s + 2*t]) | ((u32)f2bf(p[8*s + 2*t + 1]) << 16);
                    u32 b = (u32)f2bf(p[8*s + 4 + 2*t]) | ((u32)f2bf(p[8*s + 4 + 2*t + 1]) << 16);
                    asm volatile("v_permlane32_swap_b32 %0, %1" : "+v"(a), "+v"(b));
                    pa[s][t] = a; pa[s][t + 2] = b;
                }
            }
            #pragma unroll
            for (int s = 0; s < 2; ++s) {
                FRAG pau;
                pau.q = make_uint4(pa[s][0], pa[s][1], pa[s][2], pa[s][3]);
                #pragma unroll
                for (int dg = 0; dg < 4; ++dg) {
                    FRAG vf;
                    vf.q = *(const uint4*)&Vt[(dg * 32 + ql) * 40 + s * 16 + hi * 8];
                    Oa[dg] = __builtin_amdgcn_mfma_f32_32x32x16_bf16(pau.b, vf.b, Oa[dg], 0, 0, 0);
                }
            }
        }
        __syncthreads();
    }
    // epilogue: transpose through LDS, scale by 1/l, coalesced bf16 store
    float linv = 1.f / l_run;
    #pragma unroll
    for (int dg = 0; dg < 4; ++dg) {
        #pragma unroll
        for (int r = 0; r < 16; ++r)
            Ot[w][(r & 3) + ((r >> 2) << 3) + (hi << 2)][ql] = Oa[dg][r];
        __syncthreads();
        float4 v0 = *(const float4*)&Ot[w][ql][hi * 16 + 0];
        float4 v1 = *(const float4*)&Ot[w][ql][hi * 16 + 4];
        float4 v2 = *(const float4*)&Ot[w][ql][hi * 16 + 8];
        float4 v3 = *(const float4*)&Ot[w][ql][hi * 16 + 12];
        FRAG a, b;
        a.u[0] = f2bf(v0.x * linv); a.u[1] = f2bf(v0.y * linv);
        a.u[2] = f2bf(v0.z * linv); a.u[3] = f2bf(v0.w * linv);
        a.u[4] = f2bf(v1.x * linv); a.u[5] = f2bf(v1.y * linv);
        a.u[6] = f2bf(v1.z * linv); a.u[7] = f2bf(v1.w * linv);
        b.u[0] = f2bf(v2.x * linv); b.u[1] = f2bf(v2.y * linv);
        b.u[2] = f2bf(v2.z * linv); b.u[3] = f2bf(v2.w * linv);
        b.u[4] = f2bf(v3.x * linv); b.u[5] = f2bf(v3.y * linv);
        b.u[6] = f2bf(v3.z * linv); b.u[7] = f2bf(v3.w * linv);
        u16* dst = ctxb + (size_t)(i0 + w * 32 + ql) * HIDN + h * 128 + dg * 32 + hi * 16;
        *(uint4*)dst = a.q;
        *(uint4*)(dst + 8) = b.q;
        __syncthreads();
    }
}

// ---------------------------------------------------------------------------

extern "C" void kernel_launch(void* const* d_in, const int* in_sizes, int n_in,
                              void* d_out, int out_size, void* d_ws, size_t ws_size,
                              hipStream_t stream) {
    const float* x    = (const float*)d_in[0];
    const int*   und  = (const int*)d_in[1];
    const float* Wq  = (const float*)d_in[5];
    const float* bq  = (const float*)d_in[6];
    const float* Wk  = (const float*)d_in[7];
    const float* bk  = (const float*)d_in[8];
    const float* Wv  = (const float*)d_in[9];
    const float* bv  = (const float*)d_in[10];
    const float* Wo  = (const float*)d_in[11];
    const float* qnw = (const float*)d_in[12];
    const float* knw = (const float*)d_in[13];
    const float* ln1 = (const float*)d_in[14];
    const float* ln2 = (const float*)d_in[15];
    const float* Wg  = (const float*)d_in[16];
    const float* Wu  = (const float*)d_in[17];
    const float* Wd  = (const float*)d_in[18];
    float* out = (float*)d_out;

    char* W = (char*)d_ws;
    u16* WqB = (u16*)(W + 0);                    //  8,388,608
    u16* WkB = (u16*)(W + 8388608);              //  2,097,152
    u16* WvB = (u16*)(W + 10485760);             //  2,097,152
    u16* WoB = (u16*)(W + 12582912);             //  8,388,608
    u16* WgB = (u16*)(W + 20971520);             // 33,554,432
    u16* WuB = (u16*)(W + 54525952);             // 33,554,432
    u16* WdB = (u16*)(W + 88080384);             // 33,554,432
    char* R1 = W + 121634816;                    // 31,457,280 shared region
    u16* qkvb = (u16*)R1;                        // bf16 [3072][3072]
    u16* ctxb = (u16*)(R1 + 18874368);           // bf16 [3072][2048]
    u16* acth = (u16*)R1;                        // bf16 [3072][4096] (reuse)
    float* hbuf = (float*)(W + 153092096);       // 25,165,824 fp32
    u16* xnb = (u16*)(W + 178257920);            // 12,582,912 region
    u16* Kbf = xnb;                              // bf16 [4096][512] (reuse window)
    u16* Vbf = (u16*)(W + 178257920 + 4194304);
    u16* ynb = xnb;                              // reuse again
    int* inv = (int*)(W + 190840832);

    const int BIG = 1 << 30;

    inv_init_kernel<<<16, 256, 0, stream>>>(inv);
    inv_set_kernel<<<12, 256, 0, stream>>>(und, inv);

    cvt_bf16_kernel<<<2048, 256, 0, stream>>>(Wq, WqB, 524288);
    cvt_bf16_kernel<<<512,  256, 0, stream>>>(Wk, WkB, 131072);
    cvt_bf16_kernel<<<512,  256, 0, stream>>>(Wv, WvB, 131072);
    cvt_bf16_kernel<<<2048, 256, 0, stream>>>(Wo, WoB, 524288);
    cvt_bf16_kernel<<<4096, 256, 0, stream>>>(Wg, WgB, 2097152);
    cvt_bf16_kernel<<<4096, 256, 0, stream>>>(Wu, WuB, 2097152);
    cvt_bf16_kernel<<<4096, 256, 0, stream>>>(Wd, WdB, 2097152);

    // x -> rmsnorm(ln1) bf16
    rmsnorm_bf16_kernel<<<NU, 256, 0, stream>>>(x, ln1, xnb);
    // fused QKV projection + bias -> bf16 qkv [3072][3072]
    gemm_bf16_kernel<0><<<dim3(24, 24), 256, 0, stream>>>(
        xnb, 2048, WqB, WkB, WvB, 2048, 2560, 2048,
        bq, bk, bv, nullptr, qkvb, QKV_LD, 2048);
    // q-head RMSNorm in place; scatter + norm K, scatter V (bf16, packed L)
    qnorm_kernel<<<dim3(NU, 16), 64, 0, stream>>>(qkvb, qnw);
    scatter_kv_kernel<<<dim3(LPACK, 4), 64, 0, stream>>>(qkvb, inv, knw, Kbf, Vbf);
    // MFMA flash attention -> ctx bf16
    attn_mfma_kernel<<<dim3(24, 16), 256, 0, stream>>>(qkvb, Kbf, Vbf, und, ctxb);
    // h = ctx @ Wo^T + x  (fp32)
    gemm_bf16_kernel<1><<<dim3(16, 24), 256, 0, stream>>>(
        ctxb, 2048, WoB, WoB, WoB, BIG, BIG, 2048,
        nullptr, nullptr, nullptr, x, hbuf, 2048, 2048);
    // y = rmsnorm(h, ln2) bf16
    rmsnorm_bf16_kernel<<<NU, 256, 0, stream>>>(hbuf, ln2, ynb);
    // MLP in two INTER halves: act = silu(y Wg^T) * (y Wu^T); out (+=) act Wd^T
    gemm_gateup_bf16_kernel<<<dim3(32, 24), 256, 0, stream>>>(
        ynb, WgB, WuB, acth, 4096);
    gemm_bf16_kernel<1><<<dim3(16, 24), 256, 0, stream>>>(
        acth, 4096, WdB, WdB, WdB, BIG, BIG, 8192,
        nullptr, nullptr, nullptr, hbuf, out, 2048, 4096);
    gemm_gateup_bf16_kernel<<<dim3(32, 24), 256, 0, stream>>>(
        ynb, WgB + (size_t)4096 * 2048, WuB + (size_t)4096 * 2048, acth, 4096);
    gemm_bf16_kernel<1><<<dim3(16, 24), 256, 0, stream>>>(
        acth, 4096, WdB + 4096, WdB, WdB, BIG, BIG, 8192,
        nullptr, nullptr, nullptr, out, out, 2048, 4096);
}